// Round 7
// baseline (689.492 us; speedup 1.0000x reference)
//
#include <hip/hip_runtime.h>
#include <hip/hip_bf16.h>

// EdgeProposer: probs/directions/relations heads over gathered belief pairs.
// f32 in / f32 out. R6: 196us, MfmaUtil 29%, barrier-convoyed K-loop with
// only 2 blocks/CU. R7: BARRIER-FREE K-loop — A-fragments (row=ln, k=q*8+j)
// are loaded per-wave directly from the bf16 belief table (gather IS the
// fragment load); |s-t| computed in-register; B streamed from WT. No LDS /
// no __syncthreads in the K-loop -> no vmcnt(0) drains, waves free-run.
// LDS = epilogue only (51200 B) -> 3 blocks/CU.

#define DD 512
#define K3 1536
#define ROWS 128
#define LDACT 328   // 320 + 8 pad (8*41: 16B-units odd -> b128 rows spread)
#define LDH 72

typedef short bf16x8 __attribute__((ext_vector_type(8)));
typedef float f32x4 __attribute__((ext_vector_type(4)));

__device__ inline float b2f(short s) {
    union { float f; unsigned u; } v;
    v.u = ((unsigned)(unsigned short)s) << 16;
    return v.f;
}
__device__ inline short f2b(float f) {   // RNE
    union { float fl; unsigned u; } v;
    v.fl = f;
    unsigned x = v.u;
    unsigned r = x + 0x7fffu + ((x >> 16) & 1u);
    return (short)(r >> 16);
}
__device__ inline short babsdiff(short a, short b) {
    union { float f; unsigned u; } v;
    v.f = b2f(a) - b2f(b);
    return (short)((v.u & 0x7fffffffu) >> 16);
}

// ---- workspace layout (shorts) ----
#define WT_ELEMS (320 * 1536)
#define P2T_OFF WT_ELEMS
#define R2T_OFF (WT_ELEMS + 64 * 128)
#define PREP_TOT (WT_ELEMS + 2 * 64 * 128)
#define BEL_ELEMS (8192 * 512)
#define BEL_OFF PREP_TOT

// prep: blocks [0,480): LDS-tiled transpose of layer-1 weights into
// WT[320][1536]; blocks [480, ...): elementwise pw2T/rw2T/bel16.
#define TRANS_BLOCKS 480   // (1536/32) * (320/32)
#define ELEM_TOT (2 * 64 * 128 + BEL_ELEMS)

__global__ void prep_kernel(const float* __restrict__ pw1,
                            const float* __restrict__ dw1,
                            const float* __restrict__ rw1,
                            const float* __restrict__ pw2,
                            const float* __restrict__ rw2,
                            const float* __restrict__ beliefs,
                            short* __restrict__ ws) {
    const int bx = blockIdx.x, t = threadIdx.x;
    if (bx < TRANS_BLOCKS) {
        __shared__ short tile[32][33];
        const int tk = (bx / 10) * 32, tn = (bx % 10) * 32;
        const int r = t >> 5, c = t & 31;
#pragma unroll
        for (int p = 0; p < 4; p++) {
            int k = tk + r + p * 8, n = tn + c;
            float v;
            if (n < 128)      v = pw1[k * 128 + n];
            else if (n < 192) v = dw1[k * 64 + (n - 128)];
            else              v = rw1[k * 128 + (n - 192)];
            tile[r + p * 8][c] = f2b(v);
        }
        __syncthreads();
#pragma unroll
        for (int p = 0; p < 4; p++) {
            int nn = tn + r + p * 8, kk = tk + c;
            ws[(size_t)nn * K3 + kk] = tile[c][r + p * 8];
        }
    } else {
        int j = (bx - TRANS_BLOCKS) * 256 + t;
        if (j >= ELEM_TOT) return;
        if (j < 8192) {
            int n = j >> 7, k = j & 127;
            ws[P2T_OFF + j] = f2b(pw2[k * 64 + n]);
        } else if (j < 16384) {
            int jj = j - 8192;
            int n = jj >> 7, k = jj & 127;
            ws[R2T_OFF + jj] = f2b(rw2[k * 64 + n]);
        } else {
            int idx = j - 16384;
            ws[BEL_OFF + idx] = f2b(beliefs[idx]);
        }
    }
}

// ---- main fused kernel: 128 pairs per block, 256 threads (4 waves) ----
template<bool BF>
__global__ __launch_bounds__(256, 2) void edge_main(
    const float* __restrict__ beliefs, const short* __restrict__ bel16,
    const int* __restrict__ src_idx, const int* __restrict__ tgt_idx,
    const float* __restrict__ pb1, const float* __restrict__ db1,
    const float* __restrict__ rb1,
    const float* __restrict__ pb2, const float* __restrict__ pw3,
    const float* __restrict__ pb3,
    const float* __restrict__ dw2, const float* __restrict__ db2,
    const float* __restrict__ rb2,
    const short* __restrict__ WT, const short* __restrict__ pw2T,
    const short* __restrict__ rw2T,
    float* __restrict__ out, int N)
{
    // LDS: epilogue only. acts[64][328] (41984 B) + h2s (9216 B) = 51200 B.
    __shared__ __align__(16) short smem[25600];
    short (*acts)[LDACT] = (short (*)[LDACT])smem;
    short (*h2s)[LDH] = (short (*)[LDH])(smem + 64 * LDACT);

    const int t = threadIdx.x;
    const int r0 = blockIdx.x * ROWS;
    const int w = t >> 6, lane = t & 63, q = lane >> 4, ln = lane & 15;

    // per-lane row offsets for this wave's A-fragments (same for all q)
    int offS[8], offT[8];
#pragma unroll
    for (int rt = 0; rt < 8; rt++) {
        offS[rt] = src_idx[r0 + rt * 16 + ln] * DD;
        offT[rt] = tgt_idx[r0 + rt * 16 + ln] * DD;
    }

    f32x4 acc[5][8];
#pragma unroll
    for (int ct = 0; ct < 5; ct++)
#pragma unroll
        for (int rt = 0; rt < 8; rt++) acc[ct][rt] = (f32x4)(0.f);

    const int colbase = w * 80 + ln;
    const int kq = q * 8;

    // ---- barrier-free K-loop ----
    for (int kc = 0; kc < DD; kc += 32) {
        bf16x8 bS[5], bT[5], bA[5];
#pragma unroll
        for (int ct = 0; ct < 5; ct++) {
            const short* base = WT + (size_t)(colbase + ct * 16) * K3 + kc + kq;
            bS[ct] = *(const bf16x8*)(base);
            bT[ct] = *(const bf16x8*)(base + DD);
            bA[ct] = *(const bf16x8*)(base + 2 * DD);
        }
#pragma unroll
        for (int half = 0; half < 2; half++) {
            bf16x8 sF[4], tF[4];
            if constexpr (BF) {
#pragma unroll
                for (int r4 = 0; r4 < 4; r4++) {
                    sF[r4] = *(const bf16x8*)(bel16 + offS[half * 4 + r4] + kc + kq);
                    tF[r4] = *(const bf16x8*)(bel16 + offT[half * 4 + r4] + kc + kq);
                }
            } else {
#pragma unroll
                for (int r4 = 0; r4 < 4; r4++) {
                    const float* sp = beliefs + offS[half * 4 + r4] + kc + kq;
                    const float* tp = beliefs + offT[half * 4 + r4] + kc + kq;
                    float4 sa = *(const float4*)sp, sb = *(const float4*)(sp + 4);
                    float4 ta = *(const float4*)tp, tb = *(const float4*)(tp + 4);
                    float sv[8] = {sa.x, sa.y, sa.z, sa.w, sb.x, sb.y, sb.z, sb.w};
                    float tv[8] = {ta.x, ta.y, ta.z, ta.w, tb.x, tb.y, tb.z, tb.w};
#pragma unroll
                    for (int j = 0; j < 8; j++) {
                        sF[r4][j] = f2b(sv[j]);
                        tF[r4][j] = f2b(tv[j]);
                    }
                }
            }
#pragma unroll
            for (int r4 = 0; r4 < 4; r4++)
#pragma unroll
                for (int ct = 0; ct < 5; ct++)
                    acc[ct][half * 4 + r4] = __builtin_amdgcn_mfma_f32_16x16x32_bf16(
                        sF[r4], bS[ct], acc[ct][half * 4 + r4], 0, 0, 0);
#pragma unroll
            for (int r4 = 0; r4 < 4; r4++)
#pragma unroll
                for (int ct = 0; ct < 5; ct++)
                    acc[ct][half * 4 + r4] = __builtin_amdgcn_mfma_f32_16x16x32_bf16(
                        tF[r4], bT[ct], acc[ct][half * 4 + r4], 0, 0, 0);
#pragma unroll
            for (int r4 = 0; r4 < 4; r4++) {
                bf16x8 aF;
#pragma unroll
                for (int j = 0; j < 8; j++) aF[j] = babsdiff(sF[r4][j], tF[r4][j]);
#pragma unroll
                for (int ct = 0; ct < 5; ct++)
                    acc[ct][half * 4 + r4] = __builtin_amdgcn_mfma_f32_16x16x32_bf16(
                        aF, bA[ct], acc[ct][half * 4 + r4], 0, 0, 0);
            }
        }
    }

    // ---- epilogue: two 64-row halves ----
#pragma unroll
    for (int h = 0; h < 2; h++) {
        if (h == 1) __syncthreads();   // protect previous half's acts/h2s
        // phase B: bias + relu -> acts[64][320]. C/D: col=lane&15, row=q*4+reg.
#pragma unroll
        for (int ct = 0; ct < 5; ct++) {
            int col = w * 80 + ct * 16 + ln;
            float bias = (col < 128) ? pb1[col]
                       : (col < 192) ? db1[col - 128]
                                     : rb1[col - 192];
#pragma unroll
            for (int rt4 = 0; rt4 < 4; rt4++)
#pragma unroll
                for (int i = 0; i < 4; i++) {
                    int lrow = rt4 * 16 + q * 4 + i;
                    float v = acc[ct][h * 4 + rt4][i] + bias;
                    acts[lrow][col] = f2b(fmaxf(v, 0.f));
                }
        }
        __syncthreads();

        // C1: relations = relu1_r[64x128] @ rw2 + rb2
        {
            f32x4 rc[4];
#pragma unroll
            for (int rt = 0; rt < 4; rt++) rc[rt] = (f32x4)(0.f);
#pragma unroll
            for (int ks = 0; ks < 4; ks++) {
                bf16x8 bfr = *(const bf16x8*)(rw2T + (w * 16 + ln) * 128 +
                                              ks * 32 + q * 8);
#pragma unroll
                for (int rt = 0; rt < 4; rt++) {
                    bf16x8 afr = *(const bf16x8*)&acts[rt * 16 + ln][192 + ks * 32 + q * 8];
                    rc[rt] = __builtin_amdgcn_mfma_f32_16x16x32_bf16(afr, bfr, rc[rt], 0, 0, 0);
                }
            }
            int col = w * 16 + ln;
            float bias = rb2[col];
            float* rel = out + 2 * (size_t)N;
#pragma unroll
            for (int rt = 0; rt < 4; rt++)
#pragma unroll
                for (int i = 0; i < 4; i++) {
                    int grow = r0 + h * 64 + rt * 16 + q * 4 + i;
                    rel[(size_t)grow * 64 + col] = rc[rt][i] + bias;
                }
        }

        // C2: h2 = relu(relu1_p[64x128] @ pw2 + pb2) -> h2s
        {
            f32x4 pc[4];
#pragma unroll
            for (int rt = 0; rt < 4; rt++) pc[rt] = (f32x4)(0.f);
#pragma unroll
            for (int ks = 0; ks < 4; ks++) {
                bf16x8 bfr = *(const bf16x8*)(pw2T + (w * 16 + ln) * 128 +
                                              ks * 32 + q * 8);
#pragma unroll
                for (int rt = 0; rt < 4; rt++) {
                    bf16x8 afr = *(const bf16x8*)&acts[rt * 16 + ln][0 + ks * 32 + q * 8];
                    pc[rt] = __builtin_amdgcn_mfma_f32_16x16x32_bf16(afr, bfr, pc[rt], 0, 0, 0);
                }
            }
            int col = w * 16 + ln;
            float bias = pb2[col];
#pragma unroll
            for (int rt = 0; rt < 4; rt++)
#pragma unroll
                for (int i = 0; i < 4; i++) {
                    int lrow = rt * 16 + q * 4 + i;
                    h2s[lrow][col] = f2b(fmaxf(pc[rt][i] + bias, 0.f));
                }
        }
        __syncthreads();

        // C3: probs; C4: directions
        if (t < 64) {
            float s = pb3[0];
#pragma unroll 8
            for (int k = 0; k < 64; k++) s += b2f(h2s[t][k]) * pw3[k];
            float pr = 1.f / (1.f + __expf(-s));
            out[r0 + h * 64 + t] = pr;
        } else if (t < 128) {
            int lrow = t - 64;
            float s = db2[0];
#pragma unroll 8
            for (int k = 0; k < 64; k++) s += b2f(acts[lrow][128 + k]) * dw2[k];
            float dir = (1.f / (1.f + __expf(-s))) * 1.57079632679489662f;
            out[(size_t)N + r0 + h * 64 + lrow] = dir;
        }
    }
}

extern "C" void kernel_launch(void* const* d_in, const int* in_sizes, int n_in,
                              void* d_out, int out_size, void* d_ws, size_t ws_size,
                              hipStream_t stream) {
    const float* beliefs = (const float*)d_in[0];
    const int* src = (const int*)d_in[1];
    const int* tgt = (const int*)d_in[2];
    const float* pw1 = (const float*)d_in[3];
    const float* pb1 = (const float*)d_in[4];
    const float* pw2 = (const float*)d_in[5];
    const float* pb2 = (const float*)d_in[6];
    const float* pw3 = (const float*)d_in[7];
    const float* pb3 = (const float*)d_in[8];
    const float* dw1 = (const float*)d_in[9];
    const float* db1 = (const float*)d_in[10];
    const float* dw2 = (const float*)d_in[11];
    const float* db2 = (const float*)d_in[12];
    const float* rw1 = (const float*)d_in[13];
    const float* rb1 = (const float*)d_in[14];
    const float* rw2 = (const float*)d_in[15];
    const float* rb2 = (const float*)d_in[16];

    short* ws = (short*)d_ws;
    short* WT    = ws;
    short* pw2T  = ws + P2T_OFF;
    short* rw2T  = ws + R2T_OFF;
    short* bel16 = ws + BEL_OFF;
    const int N = in_sizes[1];

    const bool useBf = ws_size >= (size_t)(PREP_TOT + BEL_ELEMS) * sizeof(short);
    const int elemN = useBf ? ELEM_TOT : (2 * 64 * 128);
    const int prepBlocks = TRANS_BLOCKS + (elemN + 255) / 256;

    prep_kernel<<<prepBlocks, 256, 0, stream>>>(pw1, dw1, rw1, pw2, rw2,
                                                beliefs, ws);

    if (useBf)
        edge_main<true><<<N / ROWS, 256, 0, stream>>>(
            beliefs, bel16, src, tgt, pb1, db1, rb1, pb2, pw3, pb3,
            dw2, db2, rb2, WT, pw2T, rw2T, (float*)d_out, N);
    else
        edge_main<false><<<N / ROWS, 256, 0, stream>>>(
            beliefs, bel16, src, tgt, pb1, db1, rb1, pb2, pw3, pb3,
            dw2, db2, rb2, WT, pw2T, rw2T, (float*)d_out, N);
}

// Round 8
// 340.264 us; speedup vs baseline: 2.0263x; 2.0263x over previous
//
#include <hip/hip_runtime.h>
#include <hip/hip_bf16.h>

// EdgeProposer: probs/directions/relations heads over gathered belief pairs.
// f32 in / f32 out. Best known: R6 (196us, LDS-staged 128-row, B-outer).
// R7 (reg-blown barrier-free) proved acc[5][8]=160 leaves ~90 regs headroom:
// 2 blocks/CU is the register ceiling. R8 attacks R6's staging path:
//  - src/tgt staging via global_load_lds DMA (fragment-major LDS layout is
//    exactly wave-uniform-base + lane*16; per-lane gather source is legal)
//  - |s-t| computed once per element in a short LDS pass
//  - B-frags prefetched one (kk2,seg)-group ahead; A-frags one rt ahead.

#define DD 512
#define K3 1536
#define ROWS 128
#define LDACT 328   // 320 + 8 pad
#define LDH 72

typedef short bf16x8 __attribute__((ext_vector_type(8)));
typedef float f32x4 __attribute__((ext_vector_type(4)));

__device__ inline float b2f(short s) {
    union { float f; unsigned u; } v;
    v.u = ((unsigned)(unsigned short)s) << 16;
    return v.f;
}
__device__ inline short f2b(float f) {   // RNE
    union { float fl; unsigned u; } v;
    v.fl = f;
    unsigned x = v.u;
    unsigned r = x + 0x7fffu + ((x >> 16) & 1u);
    return (short)(r >> 16);
}
__device__ inline short babsdiff(short a, short b) {
    union { float f; unsigned u; } v;
    v.f = b2f(a) - b2f(b);
    return (short)((v.u & 0x7fffffffu) >> 16);
}

// As2 fragment-major index: [seg][kk2][rt][lane][8] (shorts)
__device__ __forceinline__ int sidx(int seg, int kk2, int rt, int lane) {
    return (((seg * 2 + kk2) * 8 + rt) * 64 + lane) * 8;
}

// ---- workspace layout (shorts) ----
#define WT_ELEMS (320 * 1536)
#define P2T_OFF WT_ELEMS
#define R2T_OFF (WT_ELEMS + 64 * 128)
#define PREP_TOT (WT_ELEMS + 2 * 64 * 128)
#define BEL_ELEMS (8192 * 512)
#define BEL_OFF PREP_TOT

#define TRANS_BLOCKS 480   // (1536/32) * (320/32)
#define ELEM_TOT (2 * 64 * 128 + BEL_ELEMS)

__global__ void prep_kernel(const float* __restrict__ pw1,
                            const float* __restrict__ dw1,
                            const float* __restrict__ rw1,
                            const float* __restrict__ pw2,
                            const float* __restrict__ rw2,
                            const float* __restrict__ beliefs,
                            short* __restrict__ ws) {
    const int bx = blockIdx.x, t = threadIdx.x;
    if (bx < TRANS_BLOCKS) {
        __shared__ short tile[32][33];
        const int tk = (bx / 10) * 32, tn = (bx % 10) * 32;
        const int r = t >> 5, c = t & 31;
#pragma unroll
        for (int p = 0; p < 4; p++) {
            int k = tk + r + p * 8, n = tn + c;
            float v;
            if (n < 128)      v = pw1[k * 128 + n];
            else if (n < 192) v = dw1[k * 64 + (n - 128)];
            else              v = rw1[k * 128 + (n - 192)];
            tile[r + p * 8][c] = f2b(v);
        }
        __syncthreads();
#pragma unroll
        for (int p = 0; p < 4; p++) {
            int nn = tn + r + p * 8, kk = tk + c;
            ws[(size_t)nn * K3 + kk] = tile[c][r + p * 8];
        }
    } else {
        int j = (bx - TRANS_BLOCKS) * 256 + t;
        if (j >= ELEM_TOT) return;
        if (j < 8192) {
            int n = j >> 7, k = j & 127;
            ws[P2T_OFF + j] = f2b(pw2[k * 64 + n]);
        } else if (j < 16384) {
            int jj = j - 8192;
            int n = jj >> 7, k = jj & 127;
            ws[R2T_OFF + jj] = f2b(rw2[k * 64 + n]);
        } else {
            int idx = j - 16384;
            ws[BEL_OFF + idx] = f2b(beliefs[idx]);
        }
    }
}

// ---- main fused kernel: 128 pairs per block, 256 threads (4 waves) ----
template<bool BF>
__global__ __launch_bounds__(256, 2) void edge_main(
    const float* __restrict__ beliefs, const short* __restrict__ bel16,
    const int* __restrict__ src_idx, const int* __restrict__ tgt_idx,
    const float* __restrict__ pb1, const float* __restrict__ db1,
    const float* __restrict__ rb1,
    const float* __restrict__ pb2, const float* __restrict__ pw3,
    const float* __restrict__ pb3,
    const float* __restrict__ dw2, const float* __restrict__ db2,
    const float* __restrict__ rb2,
    const short* __restrict__ WT, const short* __restrict__ pw2T,
    const short* __restrict__ rw2T,
    float* __restrict__ out, int N)
{
    // As2 (49152 B) aliases acts(41984)+h2s(9216)=51200 B -> 51200-B region.
    __shared__ __align__(16) short smem[25600];
    __shared__ int sIdx[ROWS], tIdx[ROWS];
    short* As2 = smem;
    short (*acts)[LDACT] = (short (*)[LDACT])smem;
    short (*h2s)[LDH] = (short (*)[LDH])(smem + 64 * LDACT);

    const int t = threadIdx.x;
    const int r0 = blockIdx.x * ROWS;
    const int w = t >> 6, lane = t & 63, q = lane >> 4, ln = lane & 15;

    if (t < ROWS) sIdx[t] = src_idx[r0 + t] * DD;
    else tIdx[t - ROWS] = tgt_idx[r0 + t - ROWS] * DD;
    __syncthreads();

    f32x4 acc[5][8];
#pragma unroll
    for (int ct = 0; ct < 5; ct++)
#pragma unroll
        for (int rt = 0; rt < 8; rt++) acc[ct][rt] = (f32x4)(0.f);

    // ---- DMA staging roles (BF path): wave w -> seg (w>>1), kk2 (w&1);
    // 8 loads (rt=0..7). Per-lane source offset; wave-uniform LDS dest.
    const int segw = w >> 1, kk2w = w & 1;
    int preoff[8];
#pragma unroll
    for (int i = 0; i < 8; i++) {
        int row = i * 16 + ln;
        int base = segw ? tIdx[row] : sIdx[row];
        preoff[i] = base + kk2w * 32 + q * 8;
    }

    // abs-pass role (all 256 threads): row rrow, 32-k half kk2p.
    const int rrow = t >> 1, kk2p = t & 1;
    const int rtp = rrow >> 4, lnp = rrow & 15;

    // manual staging role for f32 fallback (R6 pattern)
    const int srowF = sIdx[rrow], trowF = tIdx[rrow];

    const short* wtb = WT + (size_t)(w * 80 + ln) * K3 + q * 8;

    for (int k0 = 0; k0 < DD; k0 += 64) {
        if constexpr (BF) {
            // ---- DMA: src/tgt fragment tiles straight into LDS ----
#pragma unroll
            for (int i = 0; i < 8; i++) {
                const short* gp = bel16 + preoff[i] + k0;
                short* lp = As2 + sidx(segw, kk2w, i, 0);
                __builtin_amdgcn_global_load_lds(
                    (const __attribute__((address_space(1))) unsigned int*)gp,
                    (__attribute__((address_space(3))) unsigned int*)lp,
                    16, 0, 0);
            }
            __syncthreads();
            // ---- abs pass: seg2 = |seg0 - seg1| (once per element) ----
#pragma unroll
            for (int q2 = 0; q2 < 4; q2++) {
                int l64 = q2 * 16 + lnp;
                bf16x8 s8 = *(const bf16x8*)&As2[sidx(0, kk2p, rtp, l64)];
                bf16x8 t8 = *(const bf16x8*)&As2[sidx(1, kk2p, rtp, l64)];
                bf16x8 a8;
#pragma unroll
                for (int j = 0; j < 8; j++) a8[j] = babsdiff(s8[j], t8[j]);
                *(bf16x8*)&As2[sidx(2, kk2p, rtp, l64)] = a8;
            }
            __syncthreads();
        } else {
            // ---- f32 fallback: manual staging (R6) ----
            const float4* ps_ = (const float4*)(beliefs + srowF + k0 + kk2p * 32);
            const float4* pt_ = (const float4*)(beliefs + trowF + k0 + kk2p * 32);
#pragma unroll
            for (int c = 0; c < 4; c++) {
                bf16x8 sb, tb, ab;
#pragma unroll
                for (int hh = 0; hh < 2; hh++) {
                    float4 s4 = ps_[c * 2 + hh], t4 = pt_[c * 2 + hh];
                    float ss[4] = {s4.x, s4.y, s4.z, s4.w};
                    float tt[4] = {t4.x, t4.y, t4.z, t4.w};
#pragma unroll
                    for (int e = 0; e < 4; e++) {
                        int j = hh * 4 + e;
                        sb[j] = f2b(ss[e]);
                        tb[j] = f2b(tt[e]);
                        ab[j] = f2b(fabsf(ss[e] - tt[e]));
                    }
                }
                int l64 = c * 16 + lnp;
                *(bf16x8*)&As2[sidx(0, kk2p, rtp, l64)] = sb;
                *(bf16x8*)&As2[sidx(1, kk2p, rtp, l64)] = tb;
                *(bf16x8*)&As2[sidx(2, kk2p, rtp, l64)] = ab;
            }
            __syncthreads();
        }

        // ---- MFMA phase: 6 groups (kk2 x seg), B prefetched 1 group ahead,
        //      A-frag ds_read 1 rt ahead ----
        bf16x8 bbuf[2][5];
#pragma unroll
        for (int ct = 0; ct < 5; ct++)
            bbuf[0][ct] = *(const bf16x8*)(wtb + (size_t)ct * 16 * K3 + k0);
#pragma unroll
        for (int g = 0; g < 6; g++) {
            const int cur = g & 1;
            if (g < 5) {
                int gn = g + 1, kk2n = gn / 3, segn = gn % 3;
#pragma unroll
                for (int ct = 0; ct < 5; ct++)
                    bbuf[cur ^ 1][ct] = *(const bf16x8*)(wtb + (size_t)ct * 16 * K3 +
                                                         segn * DD + k0 + kk2n * 32);
            }
            const int kk2 = g / 3, seg = g % 3;
            bf16x8 afc = *(const bf16x8*)&As2[sidx(seg, kk2, 0, lane)];
#pragma unroll
            for (int rt = 0; rt < 8; rt++) {
                bf16x8 afn;
                if (rt < 7) afn = *(const bf16x8*)&As2[sidx(seg, kk2, rt + 1, lane)];
#pragma unroll
                for (int ct = 0; ct < 5; ct++)
                    acc[ct][rt] = __builtin_amdgcn_mfma_f32_16x16x32_bf16(
                        afc, bbuf[cur][ct], acc[ct][rt], 0, 0, 0);
                afc = afn;
            }
        }
        __syncthreads();
    }

    // ---- epilogue: two 64-row halves ----
#pragma unroll
    for (int h = 0; h < 2; h++) {
        if (h == 1) __syncthreads();
        // phase B: bias + relu -> acts[64][320]. C/D: col=lane&15, row=q*4+reg.
#pragma unroll
        for (int ct = 0; ct < 5; ct++) {
            int col = w * 80 + ct * 16 + ln;
            float bias = (col < 128) ? pb1[col]
                       : (col < 192) ? db1[col - 128]
                                     : rb1[col - 192];
#pragma unroll
            for (int rt4 = 0; rt4 < 4; rt4++)
#pragma unroll
                for (int i = 0; i < 4; i++) {
                    int lrow = rt4 * 16 + q * 4 + i;
                    float v = acc[ct][h * 4 + rt4][i] + bias;
                    acts[lrow][col] = f2b(fmaxf(v, 0.f));
                }
        }
        __syncthreads();

        // C1: relations = relu1_r[64x128] @ rw2 + rb2
        {
            f32x4 rc[4];
#pragma unroll
            for (int rt = 0; rt < 4; rt++) rc[rt] = (f32x4)(0.f);
#pragma unroll
            for (int ks = 0; ks < 4; ks++) {
                bf16x8 bfr = *(const bf16x8*)(rw2T + (w * 16 + ln) * 128 +
                                              ks * 32 + q * 8);
#pragma unroll
                for (int rt = 0; rt < 4; rt++) {
                    bf16x8 afr = *(const bf16x8*)&acts[rt * 16 + ln][192 + ks * 32 + q * 8];
                    rc[rt] = __builtin_amdgcn_mfma_f32_16x16x32_bf16(afr, bfr, rc[rt], 0, 0, 0);
                }
            }
            int col = w * 16 + ln;
            float bias = rb2[col];
            float* rel = out + 2 * (size_t)N;
#pragma unroll
            for (int rt = 0; rt < 4; rt++)
#pragma unroll
                for (int i = 0; i < 4; i++) {
                    int grow = r0 + h * 64 + rt * 16 + q * 4 + i;
                    rel[(size_t)grow * 64 + col] = rc[rt][i] + bias;
                }
        }

        // C2: h2 = relu(relu1_p[64x128] @ pw2 + pb2) -> h2s
        {
            f32x4 pc[4];
#pragma unroll
            for (int rt = 0; rt < 4; rt++) pc[rt] = (f32x4)(0.f);
#pragma unroll
            for (int ks = 0; ks < 4; ks++) {
                bf16x8 bfr = *(const bf16x8*)(pw2T + (w * 16 + ln) * 128 +
                                              ks * 32 + q * 8);
#pragma unroll
                for (int rt = 0; rt < 4; rt++) {
                    bf16x8 afr = *(const bf16x8*)&acts[rt * 16 + ln][0 + ks * 32 + q * 8];
                    pc[rt] = __builtin_amdgcn_mfma_f32_16x16x32_bf16(afr, bfr, pc[rt], 0, 0, 0);
                }
            }
            int col = w * 16 + ln;
            float bias = pb2[col];
#pragma unroll
            for (int rt = 0; rt < 4; rt++)
#pragma unroll
                for (int i = 0; i < 4; i++) {
                    int lrow = rt * 16 + q * 4 + i;
                    h2s[lrow][col] = f2b(fmaxf(pc[rt][i] + bias, 0.f));
                }
        }
        __syncthreads();

        // C3: probs; C4: directions
        if (t < 64) {
            float s = pb3[0];
#pragma unroll 8
            for (int k = 0; k < 64; k++) s += b2f(h2s[t][k]) * pw3[k];
            float pr = 1.f / (1.f + __expf(-s));
            out[r0 + h * 64 + t] = pr;
        } else if (t < 128) {
            int lrow = t - 64;
            float s = db2[0];
#pragma unroll 8
            for (int k = 0; k < 64; k++) s += b2f(acts[lrow][128 + k]) * dw2[k];
            float dir = (1.f / (1.f + __expf(-s))) * 1.57079632679489662f;
            out[(size_t)N + r0 + h * 64 + lrow] = dir;
        }
    }
}

extern "C" void kernel_launch(void* const* d_in, const int* in_sizes, int n_in,
                              void* d_out, int out_size, void* d_ws, size_t ws_size,
                              hipStream_t stream) {
    const float* beliefs = (const float*)d_in[0];
    const int* src = (const int*)d_in[1];
    const int* tgt = (const int*)d_in[2];
    const float* pw1 = (const float*)d_in[3];
    const float* pb1 = (const float*)d_in[4];
    const float* pw2 = (const float*)d_in[5];
    const float* pb2 = (const float*)d_in[6];
    const float* pw3 = (const float*)d_in[7];
    const float* pb3 = (const float*)d_in[8];
    const float* dw1 = (const float*)d_in[9];
    const float* db1 = (const float*)d_in[10];
    const float* dw2 = (const float*)d_in[11];
    const float* db2 = (const float*)d_in[12];
    const float* rw1 = (const float*)d_in[13];
    const float* rb1 = (const float*)d_in[14];
    const float* rw2 = (const float*)d_in[15];
    const float* rb2 = (const float*)d_in[16];

    short* ws = (short*)d_ws;
    short* WT    = ws;
    short* pw2T  = ws + P2T_OFF;
    short* rw2T  = ws + R2T_OFF;
    short* bel16 = ws + BEL_OFF;
    const int N = in_sizes[1];

    const bool useBf = ws_size >= (size_t)(PREP_TOT + BEL_ELEMS) * sizeof(short);
    const int elemN = useBf ? ELEM_TOT : (2 * 64 * 128);
    const int prepBlocks = TRANS_BLOCKS + (elemN + 255) / 256;

    prep_kernel<<<prepBlocks, 256, 0, stream>>>(pw1, dw1, rw1, pw2, rw2,
                                                beliefs, ws);

    if (useBf)
        edge_main<true><<<N / ROWS, 256, 0, stream>>>(
            beliefs, bel16, src, tgt, pb1, db1, rb1, pb2, pw3, pb3,
            dw2, db2, rb2, WT, pw2T, rw2T, (float*)d_out, N);
    else
        edge_main<false><<<N / ROWS, 256, 0, stream>>>(
            beliefs, bel16, src, tgt, pb1, db1, rb1, pb2, pw3, pb3,
            dw2, db2, rb2, WT, pw2T, rw2T, (float*)d_out, N);
}